// Round 6
// baseline (1132.328 us; speedup 1.0000x reference)
//
#include <hip/hip_runtime.h>
#include <stdint.h>

typedef unsigned short u16;
typedef _Float16 half_t;
typedef __attribute__((ext_vector_type(4))) float f32x4;
typedef __attribute__((ext_vector_type(8))) _Float16 f16x8;

#define NS_A 3.4445f
#define NS_B -4.7750f
#define NS_C 2.0315f

// scales (exact powers of 2, folded into epilogues):
//   x stored as 64*x ; a stored as 4096*a ; bmat stored as 4096*bmat
#define SX      64.0f
#define INV_SX  (1.0f / 64.0f)
#define INV_SA  (1.0f / 4096.0f)

// ---- async global->LDS, 16B per lane (wave-uniform LDS base + lane*16 implicit)
typedef const __attribute__((address_space(1))) void* as1_cvp;
typedef __attribute__((address_space(3))) void* as3_vp;
#define GLOAD_LDS16(gp, lp) \
    __builtin_amdgcn_global_load_lds((as1_cvp)(const void*)(gp), (as3_vp)(void*)(lp), 16, 0, 0)

// =======================================================================
// NT GEMM (general): C[i,j] = sum_k A[i,k] * B[j,k]
// BMt x BNt tile, BK=64, double-buffered LDS, 256 threads (4 waves, 2x2),
// 2-phase pipeline + both-sides XOR swizzle (rule #21).
// MODE 2: out_f16 = NS_A*aux + acc/4096          (x'_s; optional fused outT)
// MODE 3: out_f32 = acc/64 + bias[col]           (final)
// =======================================================================
#define BK 64

template <int MODE, bool SWZ, int BMt, int BNt>
__global__ __launch_bounds__(256, 3) void gemm_nt(
    const half_t* __restrict__ A, const half_t* __restrict__ B,
    const half_t* __restrict__ aux, const float* __restrict__ bias,
    void* __restrict__ outp, half_t* __restrict__ outpT,
    int M, int N, int K)
{
    constexpr int M_REP = BMt / 32;
    constexpr int N_REP = BNt / 32;

    __shared__ half_t As[2][BMt * BK];
    __shared__ half_t Bs[2][BNt * BK];
    const int tid  = threadIdx.x;
    const int wave = tid >> 6;
    const int lane = tid & 63;

    int bid = blockIdx.x;
    if (SWZ) {
        const int cpx = gridDim.x >> 3;
        bid = (bid & 7) * cpx + (bid >> 3);
    }
    const int nbx  = N / BNt;
    const int brow = (bid / nbx) * BMt;
    const int bcol = (bid % nbx) * BNt;
    const int wr = wave >> 1, wc = wave & 1;

    f32x4 acc[M_REP][N_REP] = {};

    // staging: chunks of 16B (8 f16), 8 chunks per row (BK=64).
    // chunk c = j*256 + tid -> row = j*32 + (tid>>3), chunk-col = tid&7
    // global source column-chunk pre-swizzled: ^ (row&7)
    const int r0  = tid >> 3;
    const int c8s = (((tid & 7) ^ ((tid >> 3) & 7))) * 8;

    const half_t* gA = A + (size_t)(brow + r0) * K + c8s;
    const half_t* gB = B + (size_t)(bcol + r0) * K + c8s;

    auto stage = [&](int buf, int kt) {
#pragma unroll
        for (int j = 0; j < BMt / 32; ++j)
            GLOAD_LDS16(gA + (size_t)(j * 32) * K + kt, &As[buf][(size_t)(j * 256 + wave * 64) * 8]);
#pragma unroll
        for (int j = 0; j < BNt / 32; ++j)
            GLOAD_LDS16(gB + (size_t)(j * 32) * K + kt, &Bs[buf][(size_t)(j * 256 + wave * 64) * 8]);
    };

    stage(0, 0);
    __syncthreads();

    const int nsteps = K / BK;
    for (int s = 0; s < nsteps; ++s) {
        const int cur = s & 1;
        if (s + 1 < nsteps) stage(cur ^ 1, (s + 1) * BK);

        f16x8 af[M_REP][2], bfr[N_REP][2];
#pragma unroll
        for (int m = 0; m < M_REP; ++m) {
            const int row = wr * (BMt / 2) + m * 16 + (lane & 15);
#pragma unroll
            for (int kk = 0; kk < 2; ++kk) {
                const int cc = (kk * 4 + (lane >> 4)) ^ (row & 7);
                af[m][kk] = *(const f16x8*)&As[cur][row * BK + cc * 8];
            }
        }
#pragma unroll
        for (int n = 0; n < N_REP; ++n) {
            const int row = wc * (BNt / 2) + n * 16 + (lane & 15);
#pragma unroll
            for (int kk = 0; kk < 2; ++kk) {
                const int cc = (kk * 4 + (lane >> 4)) ^ (row & 7);
                bfr[n][kk] = *(const f16x8*)&Bs[cur][row * BK + cc * 8];
            }
        }
#pragma unroll
        for (int kk = 0; kk < 2; ++kk)
#pragma unroll
            for (int m = 0; m < M_REP; ++m)
#pragma unroll
                for (int n = 0; n < N_REP; ++n)
                    acc[m][n] = __builtin_amdgcn_mfma_f32_16x16x32_f16(af[m][kk], bfr[n][kk], acc[m][n], 0, 0, 0);

        __syncthreads();
    }

#pragma unroll
    for (int m = 0; m < M_REP; ++m) {
#pragma unroll
        for (int n = 0; n < N_REP; ++n) {
            const int row0 = brow + wr * (BMt / 2) + m * 16 + (lane >> 4) * 4;
            const int col  = bcol + wc * (BNt / 2) + n * 16 + (lane & 15);
#pragma unroll
            for (int r = 0; r < 4; ++r) {
                const size_t idx = (size_t)(row0 + r) * N + col;
                const float v = acc[m][n][r];
                if (MODE == 2) {
                    const half_t o = (half_t)(NS_A * (float)aux[idx] + v * INV_SA);
                    ((half_t*)outp)[idx] = o;
                    if (outpT) outpT[(size_t)col * M + row0 + r] = o;
                } else {
                    ((float*)outp)[idx] = v * INV_SX + bias[col];
                }
            }
        }
    }
}

// =======================================================================
// Symmetric NT GEMM: C = A A^T (MODE 0) or C = NS_B*A + NS_C*(A A^T) (MODE 1)
// where A (and hence C) is symmetric. 64x64 tiles over the UPPER-TRIANGLE
// block grid only (N/64=32 -> 528 blocks); epilogue mirror-writes (c,r).
// Mirror values are bitwise identical to direct computation (elementwise
// product commutes; k-reduction order fixed by MFMA regardless of operand
// position; amat stored bitwise-symmetric by this same scheme).
// =======================================================================
template <int MODE>
__global__ __launch_bounds__(256, 3) void gemm_nt_sym(
    const half_t* __restrict__ A, const half_t* __restrict__ aux,
    half_t* __restrict__ outp, int N, int K)
{
    __shared__ half_t As[2][64 * BK];
    __shared__ half_t Bs[2][64 * BK];
    const int tid  = threadIdx.x;
    const int wave = tid >> 6;
    const int lane = tid & 63;

    int bid = blockIdx.x;
    {   // XCD-aware remap (528 % 8 == 0)
        const int cpx = gridDim.x >> 3;
        bid = (bid & 7) * cpx + (bid >> 3);
    }
    // triangular decode: bid -> (bi, bj), bi <= bj, 32x32 block grid
    // off(bi) = 32*bi - bi*(bi-1)/2
    int bi = (int)(32.5f - sqrtf(32.5f * 32.5f - 2.0f * (float)bid));
    bi = bi < 0 ? 0 : (bi > 31 ? 31 : bi);
    while (bi < 31 && (32 * (bi + 1) - ((bi + 1) * bi) / 2) <= bid) ++bi;
    while (bi > 0 && (32 * bi - (bi * (bi - 1)) / 2) > bid) --bi;
    const int bj = bi + (bid - (32 * bi - (bi * (bi - 1)) / 2));

    const int brow = bi * 64;
    const int bcol = bj * 64;
    const int wr = wave >> 1, wc = wave & 1;

    f32x4 acc[2][2] = {};

    const int r0  = tid >> 3;
    const int c8s = (((tid & 7) ^ ((tid >> 3) & 7))) * 8;

    const half_t* gA = A + (size_t)(brow + r0) * K + c8s;
    const half_t* gB = A + (size_t)(bcol + r0) * K + c8s;

    auto stage = [&](int buf, int kt) {
#pragma unroll
        for (int j = 0; j < 2; ++j) {
            GLOAD_LDS16(gA + (size_t)(j * 32) * K + kt, &As[buf][(size_t)(j * 256 + wave * 64) * 8]);
            GLOAD_LDS16(gB + (size_t)(j * 32) * K + kt, &Bs[buf][(size_t)(j * 256 + wave * 64) * 8]);
        }
    };

    stage(0, 0);
    __syncthreads();

    const int nsteps = K / BK;
    for (int s = 0; s < nsteps; ++s) {
        const int cur = s & 1;
        if (s + 1 < nsteps) stage(cur ^ 1, (s + 1) * BK);

        f16x8 af[2][2], bfr[2][2];
#pragma unroll
        for (int m = 0; m < 2; ++m) {
            const int row = wr * 32 + m * 16 + (lane & 15);
#pragma unroll
            for (int kk = 0; kk < 2; ++kk) {
                const int cc = (kk * 4 + (lane >> 4)) ^ (row & 7);
                af[m][kk] = *(const f16x8*)&As[cur][row * BK + cc * 8];
            }
        }
#pragma unroll
        for (int n = 0; n < 2; ++n) {
            const int row = wc * 32 + n * 16 + (lane & 15);
#pragma unroll
            for (int kk = 0; kk < 2; ++kk) {
                const int cc = (kk * 4 + (lane >> 4)) ^ (row & 7);
                bfr[n][kk] = *(const f16x8*)&Bs[cur][row * BK + cc * 8];
            }
        }
#pragma unroll
        for (int kk = 0; kk < 2; ++kk)
#pragma unroll
            for (int m = 0; m < 2; ++m)
#pragma unroll
                for (int n = 0; n < 2; ++n)
                    acc[m][n] = __builtin_amdgcn_mfma_f32_16x16x32_f16(af[m][kk], bfr[n][kk], acc[m][n], 0, 0, 0);

        __syncthreads();
    }

    // epilogue with mirror write: direct (r<=c), mirror (r<c)
#pragma unroll
    for (int m = 0; m < 2; ++m) {
#pragma unroll
        for (int n = 0; n < 2; ++n) {
            const int row0 = brow + wr * 32 + m * 16 + (lane >> 4) * 4;
            const int col  = bcol + wc * 32 + n * 16 + (lane & 15);
#pragma unroll
            for (int r = 0; r < 4; ++r) {
                const int row = row0 + r;
                const size_t idx = (size_t)row * N + col;
                const float v = acc[m][n][r];
                half_t o;
                if (MODE == 0) o = (half_t)v;
                else           o = (half_t)(NS_B * (float)aux[idx] + NS_C * v * INV_SA);
                if (row <= col) outp[idx] = o;
                if (row < col)  outp[(size_t)col * N + row] = o;
            }
        }
    }
}

// ---- deterministic Frobenius-norm reduction (fixed order, no float atomics)
__global__ __launch_bounds__(256) void k_sumsq(const float* __restrict__ w,
                                               float* __restrict__ part, int n) {
    __shared__ float s[256];
    const int per  = n / 1024;
    const int base = blockIdx.x * per;
    float acc = 0.f;
    for (int i = threadIdx.x; i < per; i += 256) {
        float v = w[base + i];
        acc += v * v;
    }
    s[threadIdx.x] = acc;
    __syncthreads();
    for (int k = 128; k > 0; k >>= 1) {
        if (threadIdx.x < k) s[threadIdx.x] += s[threadIdx.x + k];
        __syncthreads();
    }
    if (threadIdx.x == 0) part[blockIdx.x] = s[0];
}

__global__ __launch_bounds__(256) void k_scalefin(const float* __restrict__ part,
                                                  float* __restrict__ scale) {
    __shared__ float s[256];
    float acc = 0.f;
    for (int i = threadIdx.x; i < 1024; i += 256) acc += part[i];
    s[threadIdx.x] = acc;
    __syncthreads();
    for (int k = 128; k > 0; k >>= 1) {
        if (threadIdx.x < k) s[threadIdx.x] += s[threadIdx.x + k];
        __syncthreads();
    }
    if (threadIdx.x == 0) scale[0] = SX / (sqrtf(s[0]) + 1e-7f);
}

// ---- x0_s = w * (64/(|w|+eps)) -> f16
__global__ __launch_bounds__(256) void k_scale_f16(const float* __restrict__ w,
                                                   const float* __restrict__ scale,
                                                   half_t* __restrict__ o, int n) {
    const int i = (blockIdx.x * 256 + threadIdx.x) * 4;
    if (i < n) {
        const float sc = scale[0];
        float4 v = *(const float4*)(w + i);
        o[i + 0] = (half_t)(v.x * sc);
        o[i + 1] = (half_t)(v.y * sc);
        o[i + 2] = (half_t)(v.z * sc);
        o[i + 3] = (half_t)(v.w * sc);
    }
}

// ---- f32 -> f16 cast
__global__ __launch_bounds__(256) void k_cast_f16(const float* __restrict__ w,
                                                  half_t* __restrict__ o, int n) {
    const int i = (blockIdx.x * 256 + threadIdx.x) * 4;
    if (i < n) {
        float4 v = *(const float4*)(w + i);
        o[i + 0] = (half_t)v.x;
        o[i + 1] = (half_t)v.y;
        o[i + 2] = (half_t)v.z;
        o[i + 3] = (half_t)v.w;
    }
}

// ---- 16-bit NxN transpose, 64x64 LDS tiles (+1 pad)
__global__ __launch_bounds__(256) void k_transpose(const u16* __restrict__ in,
                                                   u16* __restrict__ out, int n) {
    __shared__ u16 tile[64][65];
    const int bx = blockIdx.x * 64, by = blockIdx.y * 64;
    const int tx = threadIdx.x & 63, ty = threadIdx.x >> 6;
    for (int i = ty; i < 64; i += 4) tile[i][tx] = in[(size_t)(by + i) * n + bx + tx];
    __syncthreads();
    for (int i = ty; i < 64; i += 4) out[(size_t)(bx + i) * n + by + tx] = tile[tx][i];
}

extern "C" void kernel_launch(void* const* d_in, const int* in_sizes, int n_in,
                              void* d_out, int out_size, void* d_ws, size_t ws_size,
                              hipStream_t stream) {
    const float* x = (const float*)d_in[0];
    const float* w = (const float*)d_in[1];
    const float* b = (const float*)d_in[2];
    float* out = (float*)d_out;

    const int D  = 2048;
    const int Bm = in_sizes[0] / D;      // 16384
    const int WN = D * D;
    const int XN = Bm * D;

    // ws layout: part/scale | xb0 xb1 xbTa [xbTb] amat bmat | xinb
    const size_t matB = (size_t)WN * 2;
    const bool pingpong = ws_size >= 8192 + 6 * matB + (size_t)XN * 2;

    char* ws = (char*)d_ws;
    float* part  = (float*)ws;
    float* scale = part + 1024;
    half_t* xb0  = (half_t*)(ws + 8192);
    half_t* xb1  = xb0 + WN;
    half_t* xbTa = xb1 + WN;
    half_t* xbTb = pingpong ? (xbTa + WN) : xbTa;
    half_t* amat = xbTb + WN;
    half_t* bmat = amat + WN;
    half_t* xinb = bmat + WN;

    // 1. frobenius norm -> scale; x0_s = 64*w/(|w|+eps) in f16
    k_sumsq<<<1024, 256, 0, stream>>>(w, part, WN);
    k_scalefin<<<1, 256, 0, stream>>>(part, scale);
    k_scale_f16<<<WN / 4 / 256, 256, 0, stream>>>(w, scale, xb0, WN);

    // 2. x -> f16 (final GEMM operand)
    k_cast_f16<<<XN / 4 / 256, 256, 0, stream>>>(x, xinb, XN);

    // 3. x0^T
    const dim3 tgrid(D / 64, D / 64);
    k_transpose<<<tgrid, 256, 0, stream>>>((const u16*)xb0, (u16*)xbTa, D);

    const int ns_grid  = (D / 64) * (D / 128);      // 512 blocks (mode 2)
    const int sym_grid = (D / 64) * (D / 64 + 1) / 2;  // 528 upper-tri blocks

    // 4. Newton-Schulz iterations (scaled f16)
    half_t* cur = xb0;
    half_t* nxt = xb1;
    half_t* Tr  = xbTa;   // holds cur^T
    half_t* Tw  = xbTb;   // receives nxt^T
    for (int it = 0; it < 10; ++it) {
        // a = x x^T   (symmetric, upper-tri tiles + mirror)
        gemm_nt_sym<0><<<sym_grid, 256, 0, stream>>>(cur, nullptr, amat, D, D);
        // bmat = NS_B*a + NS_C*(a a^T)   (symmetric)
        gemm_nt_sym<1><<<sym_grid, 256, 0, stream>>>(amat, amat, bmat, D, D);
        if (pingpong) {
            gemm_nt<2, true, 64, 128><<<ns_grid, 256, 0, stream>>>(bmat, Tr, cur, nullptr, nxt, Tw, D, D, D);
            half_t* tt = Tr; Tr = Tw; Tw = tt;
        } else {
            gemm_nt<2, true, 64, 128><<<ns_grid, 256, 0, stream>>>(bmat, Tr, cur, nullptr, nxt, nullptr, D, D, D);
            k_transpose<<<tgrid, 256, 0, stream>>>((const u16*)nxt, (u16*)Tr, D);
        }
        half_t* t = cur; cur = nxt; nxt = t;
    }

    // 5. out = x @ w_orth + b   (w_orth^T = Tr)
    const int fin_grid = (Bm / 128) * (D / 128);    // 2048
    gemm_nt<3, true, 128, 128><<<fin_grid, 256, 0, stream>>>(xinb, Tr, nullptr, b, out, nullptr, Bm, D, D);
}

// Round 7
// 1117.150 us; speedup vs baseline: 1.0136x; 1.0136x over previous
//
#include <hip/hip_runtime.h>
#include <stdint.h>

typedef unsigned short u16;
typedef _Float16 half_t;
typedef __attribute__((ext_vector_type(4))) float f32x4;
typedef __attribute__((ext_vector_type(8))) _Float16 f16x8;

#define NS_A 3.4445f
#define NS_B -4.7750f
#define NS_C 2.0315f

// scales (exact powers of 2, folded into epilogues):
//   x stored as 64*x ; a stored as 4096*a ; bmat stored as 4096*bmat
#define SX      64.0f
#define INV_SX  (1.0f / 64.0f)
#define INV_SA  (1.0f / 4096.0f)

// ---- async global->LDS, 16B per lane (wave-uniform LDS base + lane*16 implicit)
typedef const __attribute__((address_space(1))) void* as1_cvp;
typedef __attribute__((address_space(3))) void* as3_vp;
#define GLOAD_LDS16(gp, lp) \
    __builtin_amdgcn_global_load_lds((as1_cvp)(const void*)(gp), (as3_vp)(void*)(lp), 16, 0, 0)

// =======================================================================
// NT GEMM (NS iterations; verified R5 structure): C[i,j] = sum_k A[i,k]*B[j,k]
// 64x128 tile, BK=64, double-buffered LDS, 256 threads, 2-phase pipeline,
// both-sides XOR swizzle.
// MODE 0: out_f16 = acc                          (a_s = x_s x_s^T)
// MODE 1: out_f16 = NS_B*aux + NS_C*acc/4096     (bmat_s; acc = a_s@a_s)
// MODE 2: out_f16 = NS_A*aux + acc/4096          (x'_s; optional fused outT)
// =======================================================================
#define BK 64

template <int MODE, bool SWZ, int BMt, int BNt>
__global__ __launch_bounds__(256, 3) void gemm_nt(
    const half_t* __restrict__ A, const half_t* __restrict__ B,
    const half_t* __restrict__ aux, const float* __restrict__ bias,
    void* __restrict__ outp, half_t* __restrict__ outpT,
    int M, int N, int K)
{
    constexpr int M_REP = BMt / 32;
    constexpr int N_REP = BNt / 32;

    __shared__ half_t As[2][BMt * BK];
    __shared__ half_t Bs[2][BNt * BK];
    const int tid  = threadIdx.x;
    const int wave = tid >> 6;
    const int lane = tid & 63;

    int bid = blockIdx.x;
    if (SWZ) {
        const int cpx = gridDim.x >> 3;
        bid = (bid & 7) * cpx + (bid >> 3);
    }
    const int nbx  = N / BNt;
    const int brow = (bid / nbx) * BMt;
    const int bcol = (bid % nbx) * BNt;
    const int wr = wave >> 1, wc = wave & 1;

    f32x4 acc[M_REP][N_REP] = {};

    const int r0  = tid >> 3;
    const int c8s = (((tid & 7) ^ ((tid >> 3) & 7))) * 8;

    const half_t* gA = A + (size_t)(brow + r0) * K + c8s;
    const half_t* gB = B + (size_t)(bcol + r0) * K + c8s;

    auto stage = [&](int buf, int kt) {
#pragma unroll
        for (int j = 0; j < BMt / 32; ++j)
            GLOAD_LDS16(gA + (size_t)(j * 32) * K + kt, &As[buf][(size_t)(j * 256 + wave * 64) * 8]);
#pragma unroll
        for (int j = 0; j < BNt / 32; ++j)
            GLOAD_LDS16(gB + (size_t)(j * 32) * K + kt, &Bs[buf][(size_t)(j * 256 + wave * 64) * 8]);
    };

    stage(0, 0);
    __syncthreads();

    const int nsteps = K / BK;
    for (int s = 0; s < nsteps; ++s) {
        const int cur = s & 1;
        if (s + 1 < nsteps) stage(cur ^ 1, (s + 1) * BK);

        f16x8 af[M_REP][2], bfr[N_REP][2];
#pragma unroll
        for (int m = 0; m < M_REP; ++m) {
            const int row = wr * (BMt / 2) + m * 16 + (lane & 15);
#pragma unroll
            for (int kk = 0; kk < 2; ++kk) {
                const int cc = (kk * 4 + (lane >> 4)) ^ (row & 7);
                af[m][kk] = *(const f16x8*)&As[cur][row * BK + cc * 8];
            }
        }
#pragma unroll
        for (int n = 0; n < N_REP; ++n) {
            const int row = wc * (BNt / 2) + n * 16 + (lane & 15);
#pragma unroll
            for (int kk = 0; kk < 2; ++kk) {
                const int cc = (kk * 4 + (lane >> 4)) ^ (row & 7);
                bfr[n][kk] = *(const f16x8*)&Bs[cur][row * BK + cc * 8];
            }
        }
#pragma unroll
        for (int kk = 0; kk < 2; ++kk)
#pragma unroll
            for (int m = 0; m < M_REP; ++m)
#pragma unroll
                for (int n = 0; n < N_REP; ++n)
                    acc[m][n] = __builtin_amdgcn_mfma_f32_16x16x32_f16(af[m][kk], bfr[n][kk], acc[m][n], 0, 0, 0);

        __syncthreads();
    }

#pragma unroll
    for (int m = 0; m < M_REP; ++m) {
#pragma unroll
        for (int n = 0; n < N_REP; ++n) {
            const int row0 = brow + wr * (BMt / 2) + m * 16 + (lane >> 4) * 4;
            const int col  = bcol + wc * (BNt / 2) + n * 16 + (lane & 15);
#pragma unroll
            for (int r = 0; r < 4; ++r) {
                const size_t idx = (size_t)(row0 + r) * N + col;
                const float v = acc[m][n][r];
                if (MODE == 0) {
                    ((half_t*)outp)[idx] = (half_t)v;
                } else if (MODE == 1) {
                    ((half_t*)outp)[idx] = (half_t)(NS_B * (float)aux[idx] + NS_C * v * INV_SA);
                } else if (MODE == 2) {
                    const half_t o = (half_t)(NS_A * (float)aux[idx] + v * INV_SA);
                    ((half_t*)outp)[idx] = o;
                    if (outpT) outpT[(size_t)col * M + row0 + r] = o;
                } else {
                    ((float*)outp)[idx] = v * INV_SX + bias[col];
                }
            }
        }
    }
}

// =======================================================================
// Final GEMM: out = A @ B^T * INV_SX + bias.   A: 16384x2048, B: 2048x2048.
// 256x256 tile, 512 threads (8 waves 2Mx4N, each 128x64 out, intensity 32),
// BK=32, 4-slot LDS ring (128 KiB), prefetch depth 3 (12 gloads in flight),
// counted s_waitcnt vmcnt(12) at tile entry, raw s_barrier (NO vmcnt-0 drain
// in the main loop) -- T3+T4 mechanism.
// BK=32 => each ds_read_b128 fragment covers full 64B rows => all 32 banks
// uniformly, linear layout, no swizzle needed on either side.
// =======================================================================
__global__ __launch_bounds__(512, 2) void gemm_fin(
    const half_t* __restrict__ A, const half_t* __restrict__ B,
    const float* __restrict__ bias, float* __restrict__ out,
    int M, int N, int K)
{
    __shared__ half_t As[4][256 * 32];
    __shared__ half_t Bs[4][256 * 32];
    const int tid  = threadIdx.x;
    const int wid  = tid >> 6;
    const int lane = tid & 63;
    const int wm = wid >> 2;      // 0..1 -> 128-row half
    const int wn = wid & 3;       // 0..3 -> 64-col quadrant

    int bid = blockIdx.x;                 // gridDim.x % 8 == 0
    const int cpx = gridDim.x >> 3;
    bid = (bid & 7) * cpx + (bid >> 3);   // XCD-contiguous chunks
    const int nbx  = N >> 8;
    const int brow = (bid / nbx) << 8;
    const int bcol = (bid % nbx) << 8;

    f32x4 acc[8][4] = {};

    // staging: tile = 256 rows x 32 f16 = 1024 chunks of 16B; 512 thr x 2.
    // chunk = j*512 + tid -> row = j*128 + tid>>2, col8 = (tid&3)*8. Linear.
    const half_t* gA = A + (size_t)(brow + (tid >> 2)) * K + (tid & 3) * 8;
    const half_t* gB = B + (size_t)(bcol + (tid >> 2)) * K + (tid & 3) * 8;

    int kt_next = 96;
    auto stage = [&](int slot, int kt) {
#pragma unroll
        for (int j = 0; j < 2; ++j)
            GLOAD_LDS16(gA + (size_t)(j * 128) * K + kt, &As[slot][(j * 512 + wid * 64) * 8]);
#pragma unroll
        for (int j = 0; j < 2; ++j)
            GLOAD_LDS16(gB + (size_t)(j * 128) * K + kt, &Bs[slot][(j * 512 + wid * 64) * 8]);
    };
    auto compute = [&](int slot) {
        f16x8 af[8], bf[4];
#pragma unroll
        for (int fr = 0; fr < 8; ++fr)
            af[fr] = *(const f16x8*)&As[slot][(wm * 128 + fr * 16 + (lane & 15)) * 32 + (lane >> 4) * 8];
#pragma unroll
        for (int fc = 0; fc < 4; ++fc)
            bf[fc] = *(const f16x8*)&Bs[slot][(wn * 64 + fc * 16 + (lane & 15)) * 32 + (lane >> 4) * 8];
#pragma unroll
        for (int fr = 0; fr < 8; ++fr)
#pragma unroll
            for (int fc = 0; fc < 4; ++fc)
                acc[fr][fc] = __builtin_amdgcn_mfma_f32_16x16x32_f16(af[fr], bf[fc], acc[fr][fc], 0, 0, 0);
    };

    // prologue: tiles 0,1,2 in flight
    stage(0, 0);
    stage(1, 32);
    stage(2, 64);

    // per tile t: issue stage(t+3) [after prev end-barrier, so slot t&3's old
    // tenant t-1... is fully read]; wait vmcnt(12) -> everything older than the
    // 3 newest tiles (= tile t) has landed; barrier; compute; barrier.
#define FIN_STEP(SLOT, DOSTAGE, VMN) \
    do { \
        if (DOSTAGE) { stage((SLOT + 3) & 3, kt_next); kt_next += 32; } \
        asm volatile("s_waitcnt vmcnt(" #VMN ")" ::: "memory"); \
        __builtin_amdgcn_s_barrier(); \
        compute(SLOT); \
        __builtin_amdgcn_s_barrier(); \
    } while (0)

    const int nouter = ((K >> 5) - 4) >> 2;   // K=2048 -> 15
    for (int tt = 0; tt < nouter; ++tt) {
        FIN_STEP(0, true, 12);
        FIN_STEP(1, true, 12);
        FIN_STEP(2, true, 12);
        FIN_STEP(3, true, 12);
    }
    FIN_STEP(0, true, 12);    // t = nt-4, stages last tile
    FIN_STEP(1, false, 8);
    FIN_STEP(2, false, 4);
    FIN_STEP(3, false, 0);
#undef FIN_STEP

    // epilogue: C/D col = lane&15, row = (lane>>4)*4 + r
#pragma unroll
    for (int fr = 0; fr < 8; ++fr) {
#pragma unroll
        for (int fc = 0; fc < 4; ++fc) {
            const int row0 = brow + wm * 128 + fr * 16 + (lane >> 4) * 4;
            const int col  = bcol + wn * 64 + fc * 16 + (lane & 15);
            const float bv = bias[col];
#pragma unroll
            for (int r = 0; r < 4; ++r)
                out[(size_t)(row0 + r) * N + col] = acc[fr][fc][r] * INV_SX + bv;
        }
    }
}

// ---- deterministic Frobenius-norm reduction (fixed order, no float atomics)
__global__ __launch_bounds__(256) void k_sumsq(const float* __restrict__ w,
                                               float* __restrict__ part, int n) {
    __shared__ float s[256];
    const int per  = n / 1024;
    const int base = blockIdx.x * per;
    float acc = 0.f;
    for (int i = threadIdx.x; i < per; i += 256) {
        float v = w[base + i];
        acc += v * v;
    }
    s[threadIdx.x] = acc;
    __syncthreads();
    for (int k = 128; k > 0; k >>= 1) {
        if (threadIdx.x < k) s[threadIdx.x] += s[threadIdx.x + k];
        __syncthreads();
    }
    if (threadIdx.x == 0) part[blockIdx.x] = s[0];
}

__global__ __launch_bounds__(256) void k_scalefin(const float* __restrict__ part,
                                                  float* __restrict__ scale) {
    __shared__ float s[256];
    float acc = 0.f;
    for (int i = threadIdx.x; i < 1024; i += 256) acc += part[i];
    s[threadIdx.x] = acc;
    __syncthreads();
    for (int k = 128; k > 0; k >>= 1) {
        if (threadIdx.x < k) s[threadIdx.x] += s[threadIdx.x + k];
        __syncthreads();
    }
    if (threadIdx.x == 0) scale[0] = SX / (sqrtf(s[0]) + 1e-7f);
}

// ---- x0_s = w * (64/(|w|+eps)) -> f16
__global__ __launch_bounds__(256) void k_scale_f16(const float* __restrict__ w,
                                                   const float* __restrict__ scale,
                                                   half_t* __restrict__ o, int n) {
    const int i = (blockIdx.x * 256 + threadIdx.x) * 4;
    if (i < n) {
        const float sc = scale[0];
        float4 v = *(const float4*)(w + i);
        o[i + 0] = (half_t)(v.x * sc);
        o[i + 1] = (half_t)(v.y * sc);
        o[i + 2] = (half_t)(v.z * sc);
        o[i + 3] = (half_t)(v.w * sc);
    }
}

// ---- f32 -> f16 cast
__global__ __launch_bounds__(256) void k_cast_f16(const float* __restrict__ w,
                                                  half_t* __restrict__ o, int n) {
    const int i = (blockIdx.x * 256 + threadIdx.x) * 4;
    if (i < n) {
        float4 v = *(const float4*)(w + i);
        o[i + 0] = (half_t)v.x;
        o[i + 1] = (half_t)v.y;
        o[i + 2] = (half_t)v.z;
        o[i + 3] = (half_t)v.w;
    }
}

// ---- 16-bit NxN transpose, 64x64 LDS tiles (+1 pad)
__global__ __launch_bounds__(256) void k_transpose(const u16* __restrict__ in,
                                                   u16* __restrict__ out, int n) {
    __shared__ u16 tile[64][65];
    const int bx = blockIdx.x * 64, by = blockIdx.y * 64;
    const int tx = threadIdx.x & 63, ty = threadIdx.x >> 6;
    for (int i = ty; i < 64; i += 4) tile[i][tx] = in[(size_t)(by + i) * n + bx + tx];
    __syncthreads();
    for (int i = ty; i < 64; i += 4) out[(size_t)(bx + i) * n + by + tx] = tile[tx][i];
}

extern "C" void kernel_launch(void* const* d_in, const int* in_sizes, int n_in,
                              void* d_out, int out_size, void* d_ws, size_t ws_size,
                              hipStream_t stream) {
    const float* x = (const float*)d_in[0];
    const float* w = (const float*)d_in[1];
    const float* b = (const float*)d_in[2];
    float* out = (float*)d_out;

    const int D  = 2048;
    const int Bm = in_sizes[0] / D;      // 16384
    const int WN = D * D;
    const int XN = Bm * D;

    // ws layout: part/scale | xb0 xb1 xbTa [xbTb] amat bmat | xinb
    const size_t matB = (size_t)WN * 2;
    const bool pingpong = ws_size >= 8192 + 6 * matB + (size_t)XN * 2;

    char* ws = (char*)d_ws;
    float* part  = (float*)ws;
    float* scale = part + 1024;
    half_t* xb0  = (half_t*)(ws + 8192);
    half_t* xb1  = xb0 + WN;
    half_t* xbTa = xb1 + WN;
    half_t* xbTb = pingpong ? (xbTa + WN) : xbTa;
    half_t* amat = xbTb + WN;
    half_t* bmat = amat + WN;
    half_t* xinb = bmat + WN;

    // 1. frobenius norm -> scale; x0_s = 64*w/(|w|+eps) in f16
    k_sumsq<<<1024, 256, 0, stream>>>(w, part, WN);
    k_scalefin<<<1, 256, 0, stream>>>(part, scale);
    k_scale_f16<<<WN / 4 / 256, 256, 0, stream>>>(w, scale, xb0, WN);

    // 2. x -> f16 (final GEMM operand)
    k_cast_f16<<<XN / 4 / 256, 256, 0, stream>>>(x, xinb, XN);

    // 3. x0^T
    const dim3 tgrid(D / 64, D / 64);
    k_transpose<<<tgrid, 256, 0, stream>>>((const u16*)xb0, (u16*)xbTa, D);

    const int ns_grid = (D / 64) * (D / 128);      // 512 blocks = 2/CU

    // 4. Newton-Schulz iterations (scaled f16), 64x128 tiles (verified R5 path)
    half_t* cur = xb0;
    half_t* nxt = xb1;
    half_t* Tr  = xbTa;   // holds cur^T
    half_t* Tw  = xbTb;   // receives nxt^T
    for (int it = 0; it < 10; ++it) {
        gemm_nt<0, true, 64, 128><<<ns_grid, 256, 0, stream>>>(cur, cur, nullptr, nullptr, amat, nullptr, D, D, D);
        gemm_nt<1, true, 64, 128><<<ns_grid, 256, 0, stream>>>(amat, amat, amat, nullptr, bmat, nullptr, D, D, D);
        if (pingpong) {
            gemm_nt<2, true, 64, 128><<<ns_grid, 256, 0, stream>>>(bmat, Tr, cur, nullptr, nxt, Tw, D, D, D);
            half_t* tt = Tr; Tr = Tw; Tw = tt;
        } else {
            gemm_nt<2, true, 64, 128><<<ns_grid, 256, 0, stream>>>(bmat, Tr, cur, nullptr, nxt, nullptr, D, D, D);
            k_transpose<<<tgrid, 256, 0, stream>>>((const u16*)nxt, (u16*)Tr, D);
        }
        half_t* t = cur; cur = nxt; nxt = t;
    }

    // 5. out = x @ w_orth + b   (w_orth^T = Tr), 256^2-tile counted-vmcnt ring
    const int fin_grid = (Bm / 256) * (D / 256);    // 512
    gemm_fin<<<fin_grid, 512, 0, stream>>>(xinb, Tr, b, out, Bm, D, D);
}